// Round 7
// baseline (486.439 us; speedup 1.0000x reference)
//
#include <hip/hip_runtime.h>
#include <stdint.h>

// BinarizeLinear: out[i][j] = sum_k sign(x[i][k]) * sign(W[j][k]) + bias[j]
// R7 = R6 + SPILL FIX: __launch_bounds__(512, 1). R4-R6's (512,2) capped the
// unified VGPR/AGPR budget at 256/wave; R6's live set (~270: acc 128 in AGPR,
// 48 f32 staging, 32 a-frags, 32 b-frags, addressing) spilled ~830 MB/call to
// scratch (dispatch-0 WRITE_SIZE 962 MB vs C's 134 MB). Occupancy is LDS-bound
// (128 KiB -> 1 block/CU = 2 waves/EU) so (512,1) loses nothing.
// Structure unchanged from R6: binarize(x) fused into GEMM A-staging
// (reg-load f32 -> VALU pack -> swizzled ds_write), W pre-binarized;
// 256x256 tile, 8-phase counted-vmcnt schedule, fenced barriers.
// Exact: products are +-1, integer sums <= 2048 -> fp32-exact vs reference.

#define Mdim 16384
#define Ndim 2048
#define Kdim 2048
#define NT 16  // K-tiles of 128 i8 elements

using i32x4 = __attribute__((ext_vector_type(4))) int;

__global__ __launch_bounds__(256) void binarize_w(const float* __restrict__ w,
                                                  int8_t* __restrict__ out, int n16) {
  int i = blockIdx.x * 256 + threadIdx.x;
  if (i >= n16) return;
  const float4* p = (const float4*)w + (size_t)i * 4;
  float4 f0 = p[0], f1 = p[1], f2 = p[2], f3 = p[3];
  float s[16] = {f0.x, f0.y, f0.z, f0.w, f1.x, f1.y, f1.z, f1.w,
                 f2.x, f2.y, f2.z, f2.w, f3.x, f3.y, f3.z, f3.w};
  union { int8_t b[16]; int4 v; } u;
#pragma unroll
  for (int j = 0; j < 16; ++j) u.b[j] = s[j] > 0.0f ? (int8_t)1 : (int8_t)-1;
  ((int4*)out)[i] = u.v;
}

__device__ __forceinline__ void gl_lds16(const void* gsrc, void* ldst) {
  __builtin_amdgcn_global_load_lds(
      (const __attribute__((address_space(1))) void*)gsrc,
      (__attribute__((address_space(3))) void*)ldst, 16, 0, 0);
}

__global__ __launch_bounds__(512, 1) void bin_gemm_fused(const float* __restrict__ X,
                                                         const int8_t* __restrict__ WB,
                                                         const float* __restrict__ bias,
                                                         float* __restrict__ C) {
  // [dbuf][half][128 rows][128 B]; 128 KiB total.
  __shared__ __align__(16) int8_t As[2][2][128 * 128];
  __shared__ __align__(16) int8_t Bs[2][2][128 * 128];

  const int tid = threadIdx.x;
  const int lane = tid & 63;
  const int wid = tid >> 6;  // 0..7
  const int wm = wid >> 2;
  const int wn = wid & 3;

  // XCD swizzle: 512 blocks, %8==0 -> bijective. The 8 col-tiles sharing one
  // brow (A-slice) land on the SAME XCD -> A re-reads are L2-local.
  const int bid = blockIdx.x;
  const int swzb = (bid & 7) * 64 + (bid >> 3);
  const long brow = (long)(swzb >> 3) * 256;  // 64 row-tiles
  const long bcol = (long)(swzb & 7) * 256;   // 8 col-tiles

  // ---- B staging (gl_lds): linear dest, pre-swizzled global source slot ----
  const int srow = wid * 16 + (lane >> 3);
  const int sgcol = ((lane & 7) ^ (lane >> 3)) * 16;

  // ---- A f32 staging: quarter q = tile rows q*64..q*64+63.
  // Per lane: row-in-quarter = wid*8 + lane>>3, slot = lane&7 (16 f32 -> 16 i8).
  const int arow_q = wid * 8 + (lane >> 3);  // 0..63
  const int aslot = lane & 7;
  int awr_off[2];  // swizzled ds_write byte offset for q&1 = 0/1
#pragma unroll
  for (int qh = 0; qh < 2; ++qh) {
    const int r = qh * 64 + arow_q;
    awr_off[qh] = r * 128 + ((aslot ^ (r & 7)) * 16);
  }

  // ---- fragment ds_read byte offsets (swizzled: slot ^ (row&7)) ----
  int offA[4][2], offB[2][2];
#pragma unroll
  for (int fr = 0; fr < 4; ++fr) {
    const int ra = wm * 64 + fr * 16 + (lane & 15);
#pragma unroll
    for (int ksl = 0; ksl < 2; ++ksl) {
      const int s = ksl * 4 + (lane >> 4);
      offA[fr][ksl] = ra * 128 + ((s ^ (ra & 7)) * 16);
    }
  }
#pragma unroll
  for (int fc = 0; fc < 2; ++fc) {
    const int rb = wn * 32 + fc * 16 + (lane & 15);
#pragma unroll
    for (int ksl = 0; ksl < 2; ++ksl) {
      const int s = ksl * 4 + (lane >> 4);
      offB[fc][ksl] = rb * 128 + ((s ^ (rb & 7)) * 16);
    }
  }

  i32x4 acc[2][4][2][2] = {};  // [mh][fr][nh][fc]
  i32x4 a[4][2];
  i32x4 b0[2][2], b1[2][2];
  float4 avA[4], avB[4], avC[4];

// Fenced barrier: hardware barrier + full compiler memory fence.
#define BAR() asm volatile("s_barrier" ::: "memory")

#define ALOAD(AV, Q, KT)                                                             \
  do {                                                                               \
    const float4* p_ = (const float4*)(X + (brow + (Q)*64 + arow_q) * (long)Kdim +   \
                                       ((long)(KT) << 7) + aslot * 16);              \
    AV[0] = p_[0]; AV[1] = p_[1]; AV[2] = p_[2]; AV[3] = p_[3];                      \
  } while (0)
#define PACKW(AV, Q, DB)                                                             \
  do {                                                                               \
    unsigned int d_[4];                                                              \
    _Pragma("unroll") for (int j_ = 0; j_ < 4; ++j_) {                               \
      float4 f_ = AV[j_];                                                            \
      unsigned int c0 = f_.x > 0.0f ? 0x01u : 0xFFu;                                 \
      unsigned int c1 = f_.y > 0.0f ? 0x01u : 0xFFu;                                 \
      unsigned int c2 = f_.z > 0.0f ? 0x01u : 0xFFu;                                 \
      unsigned int c3 = f_.w > 0.0f ? 0x01u : 0xFFu;                                 \
      d_[j_] = c0 | (c1 << 8) | (c2 << 16) | (c3 << 24);                             \
    }                                                                                \
    i32x4 v_ = {(int)d_[0], (int)d_[1], (int)d_[2], (int)d_[3]};                     \
    *(i32x4*)&As[DB][(Q) >> 1][awr_off[(Q)&1]] = v_;                                 \
  } while (0)
#define STAGE_B(DB, H, KT)                                                              \
  do {                                                                                  \
    const int8_t* s0_ = WB + (bcol + (H)*128 + srow) * (long)Kdim + ((long)(KT) << 7) + \
                        sgcol;                                                          \
    gl_lds16(s0_, &Bs[DB][H][(wid * 16 + 0) * 128]);                                    \
    gl_lds16(s0_ + (long)8 * Kdim, &Bs[DB][H][(wid * 16 + 8) * 128]);                   \
  } while (0)
#define LOAD_A(DB, H)                                        \
  _Pragma("unroll") for (int fr = 0; fr < 4; ++fr)           \
  _Pragma("unroll") for (int ksl = 0; ksl < 2; ++ksl)        \
      a[fr][ksl] = *(const i32x4*)&As[DB][H][offA[fr][ksl]];
#define LOAD_B(DB, H, BB)                                    \
  _Pragma("unroll") for (int fc = 0; fc < 2; ++fc)           \
  _Pragma("unroll") for (int ksl = 0; ksl < 2; ++ksl)        \
      BB[fc][ksl] = *(const i32x4*)&Bs[DB][H][offB[fc][ksl]];
#define MFMA16(MH, NH, BB)                                                    \
  __builtin_amdgcn_s_setprio(1);                                              \
  _Pragma("unroll") for (int fr = 0; fr < 4; ++fr)                            \
  _Pragma("unroll") for (int fc = 0; fc < 2; ++fc)                            \
  _Pragma("unroll") for (int ksl = 0; ksl < 2; ++ksl)                         \
      acc[MH][fr][NH][fc] = __builtin_amdgcn_mfma_i32_16x16x64_i8(            \
          a[fr][ksl], BB[fc][ksl], acc[MH][fr][NH][fc], 0, 0, 0);             \
  __builtin_amdgcn_s_setprio(0);
#define SYNC_PRE()                                     \
  BAR();                                               \
  asm volatile("s_waitcnt lgkmcnt(0)" ::: "memory");   \
  __builtin_amdgcn_sched_barrier(0)

  // ---- prologue: B for tile0 (h0,h1) + tile1 (h1); A tiles 0,1 all quarters.
  STAGE_B(0, 0, 0); STAGE_B(0, 1, 0); STAGE_B(1, 1, 1);
#pragma unroll
  for (int T = 0; T < 2; ++T) {
#pragma unroll
    for (int q = 0; q < 4; ++q) {
      ALOAD(avA, q, T);  // auto-waitcnt before pack use
      PACKW(avA, q, T);
    }
  }
  asm volatile("s_waitcnt vmcnt(0)" ::: "memory");
  asm volatile("s_waitcnt lgkmcnt(0)" ::: "memory");
  BAR();

#pragma unroll 1
  for (int t = 0; t < NT; ++t) {
    const int db = t & 1;
    const bool pf1 = (t + 1 < NT);
    const bool pf2 = (t + 2 < NT);

    // P1: reads A-h0 + B-h0->b0; stage B-h0(t+1)->Bs[db^1][0] (last read P1(t-1));
    //     issue A q0(t+2) loads.
    LOAD_A(db, 0);
    LOAD_B(db, 0, b0);
    if (pf1) STAGE_B(db ^ 1, 0, t + 1);
    if (pf2) ALOAD(avA, 0, t + 2);
    SYNC_PRE();
    MFMA16(0, 0, b0);
    BAR();

    // P2: write q0(t+2)->As[db][0] rows 0-63 (last read P1); reads B-h1->b1;
    //     issue A q1 loads.
    if (pf2) PACKW(avA, 0, db);
    LOAD_B(db, 1, b1);
    if (pf2) ALOAD(avA, 1, t + 2);
    SYNC_PRE();
    MFMA16(0, 1, b1);
    BAR();

    // P3: write q1(t+2)->As[db][0] rows 64-127 (last read P1); reads A-h1;
    //     stage B-h1(t+2)->Bs[db][1] (last read P2); issue A q2,q3 loads.
    if (pf2) PACKW(avA, 1, db);
    LOAD_A(db, 1);
    if (pf2) {
      STAGE_B(db, 1, t + 2);
      ALOAD(avB, 2, t + 2);
      ALOAD(avC, 3, t + 2);
    }
    SYNC_PRE();
    MFMA16(1, 1, b1);
    BAR();

    // P4: write q2,q3(t+2)->As[db][1] (last read P3); no ds_reads (b0 held).
    if (pf2) {
      PACKW(avB, 2, db);
      PACKW(avC, 3, db);
    }
    SYNC_PRE();
    MFMA16(1, 0, b0);
    // Boundary: 18 VMEM ops follow P1's B-h0(t+1) gl_lds -> vmcnt(18) retires it
    // (and everything older, incl. B-h1(t+1) from P3(t-1)).
    if (t < NT - 2) {
      asm volatile("s_waitcnt vmcnt(18)" ::: "memory");
    } else {
      asm volatile("s_waitcnt vmcnt(0)" ::: "memory");
    }
    BAR();
  }

  // ---- epilogue: C/D layout col=lane&15, row=(lane>>4)*4+reg ----
#pragma unroll
  for (int nh = 0; nh < 2; ++nh) {
#pragma unroll
    for (int fc = 0; fc < 2; ++fc) {
      const long col = bcol + nh * 128 + wn * 32 + fc * 16 + (lane & 15);
      const float bj = bias[col];
#pragma unroll
      for (int mh = 0; mh < 2; ++mh) {
#pragma unroll
        for (int fr = 0; fr < 4; ++fr) {
          const long row0 = brow + mh * 128 + wm * 64 + fr * 16 + (lane >> 4) * 4;
#pragma unroll
          for (int r = 0; r < 4; ++r) {
            C[(row0 + r) * (long)Ndim + col] = (float)acc[mh][fr][nh][fc][r] + bj;
          }
        }
      }
    }
  }
#undef ALOAD
#undef PACKW
#undef STAGE_B
#undef LOAD_A
#undef LOAD_B
#undef MFMA16
#undef SYNC_PRE
#undef BAR
}

extern "C" void kernel_launch(void* const* d_in, const int* in_sizes, int n_in,
                              void* d_out, int out_size, void* d_ws, size_t ws_size,
                              hipStream_t stream) {
  const float* x = (const float*)d_in[0];
  const float* w = (const float*)d_in[1];
  const float* bias = (const float*)d_in[2];
  float* out = (float*)d_out;

  int8_t* wb = (int8_t*)d_ws;  // 4.2 MB

  const int nw16 = Ndim * Kdim / 16;  // 262144
  binarize_w<<<nw16 / 256, 256, 0, stream>>>(w, wb, nw16);

  dim3 grid((Mdim / 256) * (Ndim / 256));  // 512 blocks, %8==0
  bin_gemm_fused<<<grid, 512, 0, stream>>>(x, wb, bias, out);
}

// Round 9
// 156.579 us; speedup vs baseline: 3.1067x; 3.1067x over previous
//
#include <hip/hip_runtime.h>
#include <stdint.h>

// BinarizeLinear: out[i][j] = sum_k sign(x[i][k]) * sign(W[j][k]) + bias[j]
// R9 = R8 + RACE FIX: R8's P3 both ds_read Bs[db][1] (tile t B-h1) and
// gl_lds-staged Bs[db][1] (tile t+2) in the SAME phase -> cross-wave WAR race
// (absmax 176 ~ one wrong B half-tile). Fix: drop P3's redundant LOAD_B —
// b still holds B-h1 from P2. P4 re-reads B-h0 (written only at t+1 P1, 2
// barriers later: safe).
// Structure: fused binarize(x)-in-GEMM under the 256-unified-reg/wave cap of
// 512-thread blocks: two 16-reg f32 staging sets avE/avO; quarters of tile t+2
// load P1..P4, pack P3,P4,P1(t+1),P2(t+1). Peak live ~233 < 256.
// B: gl_lds; B-h0(t+1)@P1->Bs[db^1][0]; B-h1(t+2)@P3->Bs[db][1].
// Per-iter VMEM: P1[2+4] P2[4] P3[2+4] P4[4]=20; 18 after P1's stage ->
// boundary vmcnt(18); tail vmcnt(0).
// Exact: +-1 products, int sums <= 2048 -> fp32-exact vs reference.

#define Mdim 16384
#define Ndim 2048
#define Kdim 2048
#define NT 16  // K-tiles of 128 i8 elements

using i32x4 = __attribute__((ext_vector_type(4))) int;

__global__ __launch_bounds__(256) void binarize_w(const float* __restrict__ w,
                                                  int8_t* __restrict__ out, int n16) {
  int i = blockIdx.x * 256 + threadIdx.x;
  if (i >= n16) return;
  const float4* p = (const float4*)w + (size_t)i * 4;
  float4 f0 = p[0], f1 = p[1], f2 = p[2], f3 = p[3];
  float s[16] = {f0.x, f0.y, f0.z, f0.w, f1.x, f1.y, f1.z, f1.w,
                 f2.x, f2.y, f2.z, f2.w, f3.x, f3.y, f3.z, f3.w};
  union { int8_t b[16]; int4 v; } u;
#pragma unroll
  for (int j = 0; j < 16; ++j) u.b[j] = s[j] > 0.0f ? (int8_t)1 : (int8_t)-1;
  ((int4*)out)[i] = u.v;
}

__device__ __forceinline__ void gl_lds16(const void* gsrc, void* ldst) {
  __builtin_amdgcn_global_load_lds(
      (const __attribute__((address_space(1))) void*)gsrc,
      (__attribute__((address_space(3))) void*)ldst, 16, 0, 0);
}

__global__ __launch_bounds__(512, 1) void bin_gemm_fused(const float* __restrict__ X,
                                                         const int8_t* __restrict__ WB,
                                                         const float* __restrict__ bias,
                                                         float* __restrict__ C) {
  // [dbuf][half][128 rows][128 B]; 128 KiB total.
  __shared__ __align__(16) int8_t As[2][2][128 * 128];
  __shared__ __align__(16) int8_t Bs[2][2][128 * 128];

  const int tid = threadIdx.x;
  const int lane = tid & 63;
  const int wid = tid >> 6;  // 0..7
  const int wm = wid >> 2;
  const int wn = wid & 3;

  // XCD swizzle: 512 blocks, %8==0 -> bijective; 8 col-tiles per brow share
  // the same XCD -> X re-reads are L2-local.
  const int bid = blockIdx.x;
  const int swzb = (bid & 7) * 64 + (bid >> 3);
  const long brow = (long)(swzb >> 3) * 256;  // 64 row-tiles
  const long bcol = (long)(swzb & 7) * 256;   // 8 col-tiles

  // ---- B staging (gl_lds): linear dest, pre-swizzled global source slot ----
  const int srow = wid * 16 + (lane >> 3);
  const int sgcol = ((lane & 7) ^ (lane >> 3)) * 16;

  // ---- A f32 staging: quarter q = tile rows q*64..q*64+63.
  // Per lane: row-in-quarter = wid*8 + lane>>3, slot = lane&7 (16 f32 -> 16 i8).
  const int arow_q = wid * 8 + (lane >> 3);  // 0..63
  const int aslot = lane & 7;
  int awr_off[2];  // swizzled ds_write byte offset for q&1 = 0/1
#pragma unroll
  for (int qh = 0; qh < 2; ++qh) {
    const int r = qh * 64 + arow_q;
    awr_off[qh] = r * 128 + ((aslot ^ (r & 7)) * 16);
  }

  // ---- fragment ds_read byte offsets (swizzled: slot ^ (row&7)) ----
  int offA[4][2], offB[2][2];
#pragma unroll
  for (int fr = 0; fr < 4; ++fr) {
    const int ra = wm * 64 + fr * 16 + (lane & 15);
#pragma unroll
    for (int ksl = 0; ksl < 2; ++ksl) {
      const int s = ksl * 4 + (lane >> 4);
      offA[fr][ksl] = ra * 128 + ((s ^ (ra & 7)) * 16);
    }
  }
#pragma unroll
  for (int fc = 0; fc < 2; ++fc) {
    const int rb = wn * 32 + fc * 16 + (lane & 15);
#pragma unroll
    for (int ksl = 0; ksl < 2; ++ksl) {
      const int s = ksl * 4 + (lane >> 4);
      offB[fc][ksl] = rb * 128 + ((s ^ (rb & 7)) * 16);
    }
  }

  i32x4 acc[2][4][2][2] = {};  // [mh][fr][nh][fc]
  i32x4 a[4][2];               // A frags (live 2 phases per half)
  i32x4 b[2][2];               // B frags (B-h0: P1; B-h1: P2->P3; B-h0 again: P4)
  float4 avE[4], avO[4];       // two f32 staging sets, statically indexed

// Fenced barrier: hardware barrier + full compiler memory fence.
#define BAR() asm volatile("s_barrier" ::: "memory")

#define ALOAD(AV, Q, KT)                                                             \
  do {                                                                               \
    const float4* p_ = (const float4*)(X + (brow + (Q)*64 + arow_q) * (long)Kdim +   \
                                       ((long)(KT) << 7) + aslot * 16);              \
    AV[0] = p_[0]; AV[1] = p_[1]; AV[2] = p_[2]; AV[3] = p_[3];                      \
  } while (0)
#define PACKW(AV, Q, DB)                                                             \
  do {                                                                               \
    unsigned int d_[4];                                                              \
    _Pragma("unroll") for (int j_ = 0; j_ < 4; ++j_) {                               \
      float4 f_ = AV[j_];                                                            \
      unsigned int c0 = f_.x > 0.0f ? 0x01u : 0xFFu;                                 \
      unsigned int c1 = f_.y > 0.0f ? 0x01u : 0xFFu;                                 \
      unsigned int c2 = f_.z > 0.0f ? 0x01u : 0xFFu;                                 \
      unsigned int c3 = f_.w > 0.0f ? 0x01u : 0xFFu;                                 \
      d_[j_] = c0 | (c1 << 8) | (c2 << 16) | (c3 << 24);                             \
    }                                                                                \
    i32x4 v_ = {(int)d_[0], (int)d_[1], (int)d_[2], (int)d_[3]};                     \
    *(i32x4*)&As[DB][(Q) >> 1][awr_off[(Q)&1]] = v_;                                 \
  } while (0)
#define STAGE_B(DB, H, KT)                                                              \
  do {                                                                                  \
    const int8_t* s0_ = WB + (bcol + (H)*128 + srow) * (long)Kdim + ((long)(KT) << 7) + \
                        sgcol;                                                          \
    gl_lds16(s0_, &Bs[DB][H][(wid * 16 + 0) * 128]);                                    \
    gl_lds16(s0_ + (long)8 * Kdim, &Bs[DB][H][(wid * 16 + 8) * 128]);                   \
  } while (0)
#define LOAD_A(DB, H)                                        \
  _Pragma("unroll") for (int fr = 0; fr < 4; ++fr)           \
  _Pragma("unroll") for (int ksl = 0; ksl < 2; ++ksl)        \
      a[fr][ksl] = *(const i32x4*)&As[DB][H][offA[fr][ksl]];
#define LOAD_B(DB, H)                                        \
  _Pragma("unroll") for (int fc = 0; fc < 2; ++fc)           \
  _Pragma("unroll") for (int ksl = 0; ksl < 2; ++ksl)        \
      b[fc][ksl] = *(const i32x4*)&Bs[DB][H][offB[fc][ksl]];
#define MFMA16(MH, NH)                                                        \
  __builtin_amdgcn_s_setprio(1);                                              \
  _Pragma("unroll") for (int fr = 0; fr < 4; ++fr)                            \
  _Pragma("unroll") for (int fc = 0; fc < 2; ++fc)                            \
  _Pragma("unroll") for (int ksl = 0; ksl < 2; ++ksl)                         \
      acc[MH][fr][NH][fc] = __builtin_amdgcn_mfma_i32_16x16x64_i8(            \
          a[fr][ksl], b[fc][ksl], acc[MH][fr][NH][fc], 0, 0, 0);              \
  __builtin_amdgcn_s_setprio(0);
#define SYNC_PRE()                                     \
  BAR();                                               \
  asm volatile("s_waitcnt lgkmcnt(0)" ::: "memory");   \
  __builtin_amdgcn_sched_barrier(0)

  // ---- prologue: A tiles 0,1 (E/O interleaved pairs); B (0,h0),(0,h1),(1,h1).
  STAGE_B(0, 0, 0); STAGE_B(0, 1, 0); STAGE_B(1, 1, 1);
#pragma unroll
  for (int T = 0; T < 2; ++T) {
    ALOAD(avE, 0, T); ALOAD(avO, 1, T);
    PACKW(avE, 0, T); PACKW(avO, 1, T);
    ALOAD(avE, 2, T); ALOAD(avO, 3, T);
    PACKW(avE, 2, T); PACKW(avO, 3, T);
  }
  asm volatile("s_waitcnt vmcnt(0)" ::: "memory");
  asm volatile("s_waitcnt lgkmcnt(0)" ::: "memory");
  BAR();

#pragma unroll 1
  for (int t = 0; t < NT; ++t) {
    const int db = t & 1;
    const bool pf1 = (t + 1 < NT);
    const bool pf2 = (t + 2 < NT);
    const bool pk1 = (t >= 1) && pf1;  // packs q2,q3 of tile t+1 (loaded iter t-1)

    // P1: pack q2(t+1)->As[db^1][1] r0-63 (last read P3(t-1)); reads A-h0,B-h0;
    //     stage B-h0(t+1)->Bs[db^1][0] (last read P4(t-1)); load q0(t+2)->avE.
    if (pk1) PACKW(avE, 2, db ^ 1);
    LOAD_A(db, 0);
    LOAD_B(db, 0);
    if (pf1) STAGE_B(db ^ 1, 0, t + 1);
    if (pf2) ALOAD(avE, 0, t + 2);
    SYNC_PRE();
    MFMA16(0, 0);
    BAR();

    // P2: pack q3(t+1)->As[db^1][1] r64-127 (last read P3(t-1)); reads B-h1;
    //     load q1(t+2)->avO.
    if (pk1) PACKW(avO, 3, db ^ 1);
    LOAD_B(db, 1);
    if (pf2) ALOAD(avO, 1, t + 2);
    SYNC_PRE();
    MFMA16(0, 1);
    BAR();

    // P3: pack q0(t+2)->As[db][0] r0-63 (last read P1); reads A-h1; b holds
    //     B-h1 from P2 (NO ds_read of Bs[db][1] here -- it is being staged!);
    //     stage B-h1(t+2)->Bs[db][1] (last read P2); load q2(t+2)->avE.
    if (pf2) PACKW(avE, 0, db);
    LOAD_A(db, 1);
    if (pf2) {
      STAGE_B(db, 1, t + 2);
      ALOAD(avE, 2, t + 2);
    }
    SYNC_PRE();
    MFMA16(1, 1);
    BAR();

    // P4: pack q1(t+2)->As[db][0] r64-127 (last read P1); re-read B-h0
    //     (Bs[db][0] next written at t+1 P1: 2 barriers later, safe);
    //     load q3(t+2)->avO.
    if (pf2) PACKW(avO, 1, db);
    LOAD_B(db, 0);
    if (pf2) ALOAD(avO, 3, t + 2);
    SYNC_PRE();
    MFMA16(1, 0);
    // Boundary: 18 VMEM after B-h0(t+1)'s stage -> vmcnt(18) retires tile t+1.
    if (t < NT - 2) {
      asm volatile("s_waitcnt vmcnt(18)" ::: "memory");
    } else {
      asm volatile("s_waitcnt vmcnt(0)" ::: "memory");
    }
    BAR();
  }

  // ---- epilogue: C/D layout col=lane&15, row=(lane>>4)*4+reg ----
#pragma unroll
  for (int nh = 0; nh < 2; ++nh) {
#pragma unroll
    for (int fc = 0; fc < 2; ++fc) {
      const long col = bcol + nh * 128 + wn * 32 + fc * 16 + (lane & 15);
      const float bj = bias[col];
#pragma unroll
      for (int mh = 0; mh < 2; ++mh) {
#pragma unroll
        for (int fr = 0; fr < 4; ++fr) {
          const long row0 = brow + mh * 128 + wm * 64 + fr * 16 + (lane >> 4) * 4;
#pragma unroll
          for (int r = 0; r < 4; ++r) {
            C[(row0 + r) * (long)Ndim + col] = (float)acc[mh][fr][nh][fc][r] + bj;
          }
        }
      }
    }
  }
#undef ALOAD
#undef PACKW
#undef STAGE_B
#undef LOAD_A
#undef LOAD_B
#undef MFMA16
#undef SYNC_PRE
#undef BAR
}

extern "C" void kernel_launch(void* const* d_in, const int* in_sizes, int n_in,
                              void* d_out, int out_size, void* d_ws, size_t ws_size,
                              hipStream_t stream) {
  const float* x = (const float*)d_in[0];
  const float* w = (const float*)d_in[1];
  const float* bias = (const float*)d_in[2];
  float* out = (float*)d_out;

  int8_t* wb = (int8_t*)d_ws;  // 4.2 MB

  const int nw16 = Ndim * Kdim / 16;  // 262144
  binarize_w<<<nw16 / 256, 256, 0, stream>>>(w, wb, nw16);

  dim3 grid((Mdim / 256) * (Ndim / 256));  // 512 blocks, %8==0
  bin_gemm_fused<<<grid, 512, 0, stream>>>(x, wb, bias, out);
}

// Round 10
// 114.713 us; speedup vs baseline: 4.2405x; 1.3650x over previous
//
#include <hip/hip_runtime.h>
#include <stdint.h>

// BinarizeLinear: out[i][j] = sum_k sign(x[i][k]) * sign(W[j][k]) + bias[j]
// R10 = R3 base (separate binarize pass, i8 MFMA GEMM 256x256, counted-vmcnt)
// with the 8-phase loop MERGED into 2 fat phases/iter (4 barriers, not 8) and
// lgkmcnt(0) moved BEFORE each barrier (reads drain during barrier skew; 32-MFMA
// clusters issue immediately post-BAR and drain async while next reads issue).
// Ledger (audited): PhA(t) reads As[db][0],Bs[db][0],Bs[db][1]; stages
// Bs[db^1][0] (last read A(t-1)) + As[db^1][1] (last read B(t-1)). PhB(t) reads
// As[db][1]; stages As[db][0]+Bs[db][1] (last read A(t), drained pre-BAR).
// No phase stages a region it reads (R8 lesson). vmcnt(4)/iter at end of PhB
// retires tile t+1. Exact: +-1 products, int sums <= 2048 -> fp32-exact.

#define Mdim 16384
#define Ndim 2048
#define Kdim 2048
#define NT 16  // K-tiles of 128 i8 elements

using i32x4 = __attribute__((ext_vector_type(4))) int;

__global__ __launch_bounds__(256) void binarize_both(const float* __restrict__ x,
                                                     const float* __restrict__ w,
                                                     int8_t* __restrict__ out,
                                                     int nx16, int ntot16) {
  int i = blockIdx.x * 256 + threadIdx.x;
  if (i >= ntot16) return;
  const float4* p = (i < nx16) ? ((const float4*)x + (size_t)i * 4)
                               : ((const float4*)w + (size_t)(i - nx16) * 4);
  float4 f0 = p[0], f1 = p[1], f2 = p[2], f3 = p[3];
  float s[16] = {f0.x, f0.y, f0.z, f0.w, f1.x, f1.y, f1.z, f1.w,
                 f2.x, f2.y, f2.z, f2.w, f3.x, f3.y, f3.z, f3.w};
  union { int8_t b[16]; int4 v; } u;
#pragma unroll
  for (int j = 0; j < 16; ++j) u.b[j] = s[j] > 0.0f ? (int8_t)1 : (int8_t)-1;
  ((int4*)out)[i] = u.v;  // xb then wb, contiguous
}

__device__ __forceinline__ void gl_lds16(const void* gsrc, void* ldst) {
  __builtin_amdgcn_global_load_lds(
      (const __attribute__((address_space(1))) void*)gsrc,
      (__attribute__((address_space(3))) void*)ldst, 16, 0, 0);
}

__global__ __launch_bounds__(512, 1) void bin_gemm_i8_4ph(const int8_t* __restrict__ A,
                                                          const int8_t* __restrict__ W,
                                                          const float* __restrict__ bias,
                                                          float* __restrict__ C) {
  // [dbuf][half][128 rows][128 B]; 128 KiB total.
  __shared__ __align__(16) int8_t As[2][2][128 * 128];
  __shared__ __align__(16) int8_t Bs[2][2][128 * 128];

  const int tid = threadIdx.x;
  const int lane = tid & 63;
  const int wid = tid >> 6;  // 0..7
  const int wm = wid >> 2;
  const int wn = wid & 3;

  // XCD swizzle: 512 blocks, %8==0 -> bijective.
  const int bid = blockIdx.x;
  const int swzb = (bid & 7) * 64 + (bid >> 3);
  const long brow = (long)(swzb >> 3) * 256;  // 64 row-tiles
  const long bcol = (long)(swzb & 7) * 256;   // 8 col-tiles

  // ---- staging: linear LDS dest, pre-swizzled global source slot ----
  const int srow = wid * 16 + (lane >> 3);
  const int sgcol = ((lane & 7) ^ (lane >> 3)) * 16;

  // ---- fragment ds_read byte offsets (swizzled: slot ^ (row&7)) ----
  int offA[4][2], offB[2][2];
#pragma unroll
  for (int fr = 0; fr < 4; ++fr) {
    const int ra = wm * 64 + fr * 16 + (lane & 15);
#pragma unroll
    for (int ksl = 0; ksl < 2; ++ksl) {
      const int s = ksl * 4 + (lane >> 4);
      offA[fr][ksl] = ra * 128 + ((s ^ (ra & 7)) * 16);
    }
  }
#pragma unroll
  for (int fc = 0; fc < 2; ++fc) {
    const int rb = wn * 32 + fc * 16 + (lane & 15);
#pragma unroll
    for (int ksl = 0; ksl < 2; ++ksl) {
      const int s = ksl * 4 + (lane >> 4);
      offB[fc][ksl] = rb * 128 + ((s ^ (rb & 7)) * 16);
    }
  }

  i32x4 acc[2][4][2][2] = {};  // [mh][fr][nh][fc]
  i32x4 a[4][2];               // current-mh A frags
  i32x4 b0[2][2], b1[2][2];    // B-h0 / B-h1, loaded PhA, live through PhB

#define BAR() asm volatile("s_barrier" ::: "memory")
#define STAGE_A(DB, H, KT)                                                              \
  do {                                                                                  \
    const int8_t* s0_ = A + (brow + (H)*128 + srow) * (long)Kdim + ((long)(KT) << 7) +  \
                        sgcol;                                                          \
    gl_lds16(s0_, &As[DB][H][(wid * 16 + 0) * 128]);                                    \
    gl_lds16(s0_ + (long)8 * Kdim, &As[DB][H][(wid * 16 + 8) * 128]);                   \
  } while (0)
#define STAGE_B(DB, H, KT)                                                              \
  do {                                                                                  \
    const int8_t* s0_ = W + (bcol + (H)*128 + srow) * (long)Kdim + ((long)(KT) << 7) +  \
                        sgcol;                                                          \
    gl_lds16(s0_, &Bs[DB][H][(wid * 16 + 0) * 128]);                                    \
    gl_lds16(s0_ + (long)8 * Kdim, &Bs[DB][H][(wid * 16 + 8) * 128]);                   \
  } while (0)
#define LOAD_A(DB, H)                                        \
  _Pragma("unroll") for (int fr = 0; fr < 4; ++fr)           \
  _Pragma("unroll") for (int ksl = 0; ksl < 2; ++ksl)        \
      a[fr][ksl] = *(const i32x4*)&As[DB][H][offA[fr][ksl]];
#define LOAD_B(DB, H, BB)                                    \
  _Pragma("unroll") for (int fc = 0; fc < 2; ++fc)           \
  _Pragma("unroll") for (int ksl = 0; ksl < 2; ++ksl)        \
      BB[fc][ksl] = *(const i32x4*)&Bs[DB][H][offB[fc][ksl]];
#define MFMA16(MH, NH, BB)                                                    \
  _Pragma("unroll") for (int fr = 0; fr < 4; ++fr)                            \
  _Pragma("unroll") for (int fc = 0; fc < 2; ++fc)                            \
  _Pragma("unroll") for (int ksl = 0; ksl < 2; ++ksl)                         \
      acc[MH][fr][NH][fc] = __builtin_amdgcn_mfma_i32_16x16x64_i8(            \
          a[fr][ksl], BB[fc][ksl], acc[MH][fr][NH][fc], 0, 0, 0);

  // ---- prologue: tile0 full (8 loads) + tile1 A-h0, B-h1 (4 loads).
  // (tile1's B-h0 and A-h1 are staged in PhA(0) per the steady schedule.)
  STAGE_A(0, 0, 0); STAGE_A(0, 1, 0); STAGE_B(0, 0, 0); STAGE_B(0, 1, 0);
  STAGE_A(1, 0, 1); STAGE_B(1, 1, 1);
  asm volatile("s_waitcnt vmcnt(4)" ::: "memory");  // tile0 resident
  BAR();

#pragma unroll 1
  for (int t = 0; t < NT; ++t) {
    const int db = t & 1;
    const bool pf1 = (t + 1 < NT);
    const bool pf2 = (t + 2 < NT);

    // ---- Phase A: reads A-h0, B-h0, B-h1 (tile t);
    //      stages B-h0(t+1)->Bs[db^1][0] (last read PhA(t-1), >=2 bars) and
    //             A-h1(t+1)->As[db^1][1] (last read PhB(t-1), >=1 bar).
    LOAD_A(db, 0);
    LOAD_B(db, 0, b0);
    LOAD_B(db, 1, b1);
    if (pf1) {
      STAGE_B(db ^ 1, 0, t + 1);
      STAGE_A(db ^ 1, 1, t + 1);
    }
    asm volatile("s_waitcnt lgkmcnt(0)" ::: "memory");  // reads drained pre-BAR
    BAR();
    __builtin_amdgcn_sched_barrier(0);
    __builtin_amdgcn_s_setprio(1);
    MFMA16(0, 0, b0);
    MFMA16(0, 1, b1);
    __builtin_amdgcn_s_setprio(0);
    BAR();

    // ---- Phase B: reads A-h1 (tile t); b0/b1 held in regs;
    //      stages A-h0(t+2)->As[db][0] and B-h1(t+2)->Bs[db][1]
    //      (both last read PhA(t), drained at PhA's pre-BAR lgkm, >=1 bar).
    LOAD_A(db, 1);
    if (pf2) {
      STAGE_A(db, 0, t + 2);
      STAGE_B(db, 1, t + 2);
    }
    asm volatile("s_waitcnt lgkmcnt(0)" ::: "memory");
    BAR();
    __builtin_amdgcn_sched_barrier(0);
    __builtin_amdgcn_s_setprio(1);
    MFMA16(1, 1, b1);
    MFMA16(1, 0, b0);
    __builtin_amdgcn_s_setprio(0);
    // Boundary: newest 4 outstanding = PhB(t)'s t+2 stages; vmcnt(4) retires
    // PhA(t)'s t+1 stages and older -> tile t+1 fully resident.
    if (t < NT - 2) {
      asm volatile("s_waitcnt vmcnt(4)" ::: "memory");
    } else {
      asm volatile("s_waitcnt vmcnt(0)" ::: "memory");
    }
    BAR();
  }

  // ---- epilogue: C/D layout col=lane&15, row=(lane>>4)*4+reg ----
#pragma unroll
  for (int nh = 0; nh < 2; ++nh) {
#pragma unroll
    for (int fc = 0; fc < 2; ++fc) {
      const long col = bcol + nh * 128 + wn * 32 + fc * 16 + (lane & 15);
      const float bj = bias[col];
#pragma unroll
      for (int mh = 0; mh < 2; ++mh) {
#pragma unroll
        for (int fr = 0; fr < 4; ++fr) {
          const long row0 = brow + mh * 128 + wm * 64 + fr * 16 + (lane >> 4) * 4;
#pragma unroll
          for (int r = 0; r < 4; ++r) {
            C[(row0 + r) * (long)Ndim + col] = (float)acc[mh][fr][nh][fc][r] + bj;
          }
        }
      }
    }
  }
#undef BAR
#undef STAGE_A
#undef STAGE_B
#undef LOAD_A
#undef LOAD_B
#undef MFMA16
}

extern "C" void kernel_launch(void* const* d_in, const int* in_sizes, int n_in,
                              void* d_out, int out_size, void* d_ws, size_t ws_size,
                              hipStream_t stream) {
  const float* x = (const float*)d_in[0];
  const float* w = (const float*)d_in[1];
  const float* bias = (const float*)d_in[2];
  float* out = (float*)d_out;

  int8_t* xb = (int8_t*)d_ws;             // 33.5 MB
  int8_t* wb = xb + (size_t)Mdim * Kdim;  // + 4.2 MB (ws >= 37.8 MB)

  const int nx16 = Mdim * Kdim / 16;
  const int nw16 = Ndim * Kdim / 16;
  const int ntot16 = nx16 + nw16;
  binarize_both<<<(ntot16 + 255) / 256, 256, 0, stream>>>(x, w, xb, nx16, ntot16);

  dim3 grid((Mdim / 256) * (Ndim / 256));  // 512 blocks, %8==0
  bin_gemm_i8_4ph<<<grid, 512, 0, stream>>>(xb, wb, bias, out);
}